// Round 1
// baseline (837.425 us; speedup 1.0000x reference)
//
#include <hip/hip_runtime.h>
#include <hip/hip_bf16.h>
#include <math.h>

#define B_ 2
#define L_ 2048
#define D_ 1024
#define K_ 32
#define M_ 4
#define H_ 32
#define AH_ 4
#define DH_ 28
#define CK_ 4
#define TOTAL_ 2208
#define BL_ (B_*L_)
#define CL_ 64
#define NC_ (L_/CL_)

#define GBM 128
#define GBN 128
#define GBK 16

// ---------------- fp32 tiled GEMM: C[M,N] = A[M,K] @ B[K,N], all row-major ----
__global__ __launch_bounds__(256) void gemm_f32(const float* __restrict__ A,
                                                const float* __restrict__ Bm,
                                                float* __restrict__ C,
                                                int M, int N, int Kd) {
    __shared__ float As[GBK][GBM + 4];
    __shared__ float Bs[GBK][GBN + 4];
    int tid = threadIdx.x;
    int bn = blockIdx.x, bm = blockIdx.y;
    int m0 = bm * GBM, n0 = bn * GBN;
    int tx = tid & 15, ty = tid >> 4;
    float acc[8][8];
#pragma unroll
    for (int i = 0; i < 8; ++i)
#pragma unroll
        for (int j = 0; j < 8; ++j) acc[i][j] = 0.f;

    for (int k0 = 0; k0 < Kd; k0 += GBK) {
        // A tile: 128 rows x 16 cols, float4 along k
#pragma unroll
        for (int i = 0; i < 2; ++i) {
            int f = tid * 2 + i;
            int mm = f >> 2;
            int kq = (f & 3) * 4;
            int gm = m0 + mm;
            float4 v = make_float4(0.f, 0.f, 0.f, 0.f);
            if (gm < M) v = *(const float4*)(A + (size_t)gm * Kd + k0 + kq);
            As[kq + 0][mm] = v.x;
            As[kq + 1][mm] = v.y;
            As[kq + 2][mm] = v.z;
            As[kq + 3][mm] = v.w;
        }
        // B tile: 16 rows x 128 cols, float4 along n
#pragma unroll
        for (int i = 0; i < 2; ++i) {
            int f = tid * 2 + i;
            int kk = f >> 5;
            int nq = (f & 31) * 4;
            int gn = n0 + nq;
            const float* bp = Bm + (size_t)(k0 + kk) * N;
            float4 v = make_float4(0.f, 0.f, 0.f, 0.f);
            if (gn + 3 < N) {
                v = *(const float4*)(bp + gn);
            } else {
                if (gn + 0 < N) v.x = bp[gn + 0];
                if (gn + 1 < N) v.y = bp[gn + 1];
                if (gn + 2 < N) v.z = bp[gn + 2];
                if (gn + 3 < N) v.w = bp[gn + 3];
            }
            *(float4*)&Bs[kk][nq] = v;
        }
        __syncthreads();
#pragma unroll
        for (int kk = 0; kk < GBK; ++kk) {
            float4 a0 = *(float4*)&As[kk][ty * 8];
            float4 a1 = *(float4*)&As[kk][ty * 8 + 4];
            float4 b0 = *(float4*)&Bs[kk][tx * 8];
            float4 b1 = *(float4*)&Bs[kk][tx * 8 + 4];
            float a[8] = {a0.x, a0.y, a0.z, a0.w, a1.x, a1.y, a1.z, a1.w};
            float b[8] = {b0.x, b0.y, b0.z, b0.w, b1.x, b1.y, b1.z, b1.w};
#pragma unroll
            for (int i = 0; i < 8; ++i)
#pragma unroll
                for (int j = 0; j < 8; ++j) acc[i][j] += a[i] * b[j];
        }
        __syncthreads();
    }
#pragma unroll
    for (int i = 0; i < 8; ++i) {
        int gm = m0 + ty * 8 + i;
        if (gm >= M) continue;
#pragma unroll
        for (int j = 0; j < 8; j += 4) {
            int gn = n0 + tx * 8 + j;
            if (gn + 3 < N) {
                *(float4*)(C + (size_t)gm * N + gn) =
                    make_float4(acc[i][j], acc[i][j + 1], acc[i][j + 2], acc[i][j + 3]);
            } else {
                for (int q = 0; q < 4; ++q)
                    if (gn + q < N) C[(size_t)gm * N + gn + q] = acc[i][j + q];
            }
        }
    }
}

// ---------------- causal depthwise conv --------------------------------------
__global__ void conv_kernel(const float* __restrict__ z, const float* __restrict__ cw,
                            const float* __restrict__ cb, float* __restrict__ zc) {
    int idx = blockIdx.x * 256 + threadIdx.x;
    if (idx >= BL_ * TOTAL_) return;
    int c = idx % TOTAL_;
    int bl = idx / TOTAL_;
    int l = bl % L_;
    float acc = cb[c];
#pragma unroll
    for (int t = 0; t < CK_; ++t) {
        int ls = l - (CK_ - 1) + t;
        if (ls >= 0) acc += z[(size_t)(bl - (CK_ - 1) + t) * TOTAL_ + c] * cw[t * TOTAL_ + c];
    }
    zc[idx] = acc;
}

// ---------------- scan pass 1: per-chunk sums --------------------------------
__global__ __launch_bounds__(128) void pass1(const float* __restrict__ zc,
                                             const float* __restrict__ mask,
                                             const float* __restrict__ theta_base,
                                             const float* __restrict__ trs_,
                                             const float* __restrict__ dslopes,
                                             const float* __restrict__ aslopes,
                                             const float* __restrict__ sscale_,
                                             float* __restrict__ cs_re,
                                             float* __restrict__ cs_im,
                                             float* __restrict__ cs_den) {
    int nc = blockIdx.x, k = blockIdx.y, b = blockIdx.z;
    int hm = threadIdx.x;
    int h = hm >> 2, m = hm & 3;
    float raw = (k < DH_) ? dslopes[k] : aslopes[k - DH_];
    float slope = log1pf(expf(raw));
    float sscale = sscale_[k];
    float trs = trs_[k];
    float tb = theta_base[k * M_ + m];
    const float PI3 = 1.04719755119659775f;
    float acc_re = 0.f, acc_im = 0.f, acc_den = 0.f;
    int l0 = nc * CL_;
    for (int i = 0; i < CL_; ++i) {
        int l = l0 + i;
        size_t rowz = (size_t)(b * L_ + l) * TOTAL_;
        float mval = mask[b * L_ + l];
        float s_raw = zc[rowz + 2 * D_ + k] * mval;
        float tr = zc[rowz + 2 * D_ + K_ + k * M_ + m];
        float xv = zc[rowz + k * H_ + h] * mval;
        float arg = fminf(fmaxf(sscale * s_raw, -20.f), 20.f);
        float p = expf(arg) * mval;
        float tw = (k < DH_) ? expf(-slope * (float)(L_ - 1 - l)) : expf(-slope * (float)l);
        float pw = p * tw;
        float td = tr / (1.f + fabsf(tr));
        float theta = tb + trs * (td * PI3);
        float sv, cv;
        sincosf(xv * theta, &sv, &cv);
        acc_re += pw * cv;
        acc_im += pw * sv;
        acc_den += pw;
    }
    size_t o = ((size_t)((b * K_ + k) * NC_ + nc)) * 128 + hm;
    cs_re[o] = acc_re;
    cs_im[o] = acc_im;
    if (hm == 0) cs_den[(b * K_ + k) * NC_ + nc] = acc_den;
}

// ---------------- scan pass 2: exclusive scan of chunk sums ------------------
__global__ void pass2(float* cs_re, float* cs_im, float* cs_den) {
    int seq = blockIdx.x * 256 + threadIdx.x;
    if (seq >= B_ * K_ * 257) return;
    int bk = seq / 257;
    int ch = seq % 257;
    float* base;
    int stride;
    if (ch < 128) { base = cs_re + (size_t)bk * NC_ * 128 + ch; stride = 128; }
    else if (ch < 256) { base = cs_im + (size_t)bk * NC_ * 128 + (ch - 128); stride = 128; }
    else { base = cs_den + (size_t)bk * NC_; stride = 1; }
    float run = 0.f;
    for (int i = 0; i < NC_; ++i) {
        float v = base[(size_t)i * stride];
        base[(size_t)i * stride] = run;
        run += v;
    }
}

// ---------------- scan pass 3: replay + normalize + per-head matvec + gate ---
__global__ __launch_bounds__(128) void pass3(const float* __restrict__ zc,
                                             const float* __restrict__ mask,
                                             const float* __restrict__ theta_base,
                                             const float* __restrict__ trs_,
                                             const float* __restrict__ dslopes,
                                             const float* __restrict__ aslopes,
                                             const float* __restrict__ sscale_,
                                             const float* __restrict__ nscale,
                                             const float* __restrict__ Wre,
                                             const float* __restrict__ Wim,
                                             const float* __restrict__ cs_re,
                                             const float* __restrict__ cs_im,
                                             const float* __restrict__ cs_den,
                                             float* __restrict__ g) {
    __shared__ float s_red[2];
    __shared__ float s_ren[128];
    __shared__ float s_imn[128];
    __shared__ float s_y[128];
    int nc = blockIdx.x, k = blockIdx.y, b = blockIdx.z;
    int tid = threadIdx.x;
    int hm = tid;
    int h = hm >> 2, m = hm & 3;
    int lane = tid & 63, wid = tid >> 6;
    int hout = tid & 31, part = tid >> 5;

    float raw = (k < DH_) ? dslopes[k] : aslopes[k - DH_];
    float slope = log1pf(expf(raw));
    float sscale = sscale_[k];
    float trs = trs_[k];
    float tb = theta_base[k * M_ + m];
    const float PI3 = 1.04719755119659775f;

    size_t o = ((size_t)((b * K_ + k) * NC_ + nc)) * 128 + hm;
    float acc_re = cs_re[o];
    float acc_im = cs_im[o];
    float den = cs_den[(b * K_ + k) * NC_ + nc];
    float ns_re = nscale[hm];
    float ns_im = nscale[128 + hm];

    int l0 = nc * CL_;
    for (int i = 0; i < CL_; ++i) {
        int l = l0 + i;
        size_t rowz = (size_t)(b * L_ + l) * TOTAL_;
        float mval = mask[b * L_ + l];
        float s_raw = zc[rowz + 2 * D_ + k] * mval;
        float tr = zc[rowz + 2 * D_ + K_ + k * M_ + m];
        float xv = zc[rowz + k * H_ + h] * mval;
        float arg = fminf(fmaxf(sscale * s_raw, -20.f), 20.f);
        float p = expf(arg) * mval;
        float tw = (k < DH_) ? expf(-slope * (float)(L_ - 1 - l)) : expf(-slope * (float)l);
        float pw = p * tw;
        float td = tr / (1.f + fabsf(tr));
        float theta = tb + trs * (td * PI3);
        float sv, cv;
        sincosf(xv * theta, &sv, &cv);
        acc_re += pw * cv;
        acc_im += pw * sv;
        den += pw;

        float inv = 1.f / fmaxf(den, 1e-4f);
        float re = acc_re * inv;
        float im = acc_im * inv;
        float sq = re * re + im * im;
        float v = sq;
#pragma unroll
        for (int off = 32; off > 0; off >>= 1) v += __shfl_xor(v, off, 64);
        if (lane == 0) s_red[wid] = v;
        __syncthreads();
        float ms = (s_red[0] + s_red[1]) * (1.0f / 256.0f);
        float rsq = rsqrtf(ms + 1e-5f);
        s_ren[hm] = re * rsq * ns_re;
        s_imn[hm] = im * rsq * ns_im;
        __syncthreads();
        float sum = 0.f;
#pragma unroll 8
        for (int q = 0; q < 32; ++q) {
            int hm2 = part * 32 + q;
            sum += s_ren[hm2] * Wre[hm2 * 32 + hout] + s_imn[hm2] * Wim[hm2 * 32 + hout];
        }
        s_y[part * 32 + hout] = sum;
        __syncthreads();
        if (part == 0) {
            float yv = s_y[hout] + s_y[32 + hout] + s_y[64 + hout] + s_y[96 + hout];
            float zg = zc[rowz + D_ + k * H_ + hout];
            float gate = zg / (1.f + expf(-zg));
            g[(size_t)(b * L_ + l) * D_ + k * H_ + hout] = yv * gate;
        }
        __syncthreads();
    }
}

extern "C" void kernel_launch(void* const* d_in, const int* in_sizes, int n_in,
                              void* d_out, int out_size, void* d_ws, size_t ws_size,
                              hipStream_t stream) {
    const float* x = (const float*)d_in[0];
    const float* mask = (const float*)d_in[1];
    const float* W_in = (const float*)d_in[2];
    const float* conv_w = (const float*)d_in[3];
    const float* conv_b = (const float*)d_in[4];
    const float* theta_base = (const float*)d_in[5];
    const float* trs = (const float*)d_in[6];
    const float* dsl = (const float*)d_in[7];
    const float* asl = (const float*)d_in[8];
    const float* ssc = (const float*)d_in[9];
    const float* nsc = (const float*)d_in[10];
    const float* Wre = (const float*)d_in[11];
    const float* Wim = (const float*)d_in[12];
    const float* Wout = (const float*)d_in[13];
    float* out = (float*)d_out;

    char* ws = (char*)d_ws;
    float* z = (float*)(ws);                       // 4096*2208 = 36,175,872 B
    float* zc = (float*)(ws + 36175872ULL);        // 36,175,872 B
    float* g = (float*)(ws + 72351744ULL);         // 16,777,216 B
    float* cs_re = (float*)(ws + 89128960ULL);     // 1,048,576 B
    float* cs_im = (float*)(ws + 90177536ULL);     // 1,048,576 B
    float* cs_den = (float*)(ws + 91226112ULL);    // 8,192 B

    gemm_f32<<<dim3((TOTAL_ + GBN - 1) / GBN, BL_ / GBM), 256, 0, stream>>>(
        x, W_in, z, BL_, TOTAL_, D_);
    conv_kernel<<<(BL_ * TOTAL_ + 255) / 256, 256, 0, stream>>>(z, conv_w, conv_b, zc);
    pass1<<<dim3(NC_, K_, B_), 128, 0, stream>>>(zc, mask, theta_base, trs, dsl, asl, ssc,
                                                 cs_re, cs_im, cs_den);
    pass2<<<(B_ * K_ * 257 + 255) / 256, 256, 0, stream>>>(cs_re, cs_im, cs_den);
    pass3<<<dim3(NC_, K_, B_), 128, 0, stream>>>(zc, mask, theta_base, trs, dsl, asl, ssc,
                                                 nsc, Wre, Wim, cs_re, cs_im, cs_den, g);
    gemm_f32<<<dim3(D_ / GBN, BL_ / GBM), 256, 0, stream>>>(g, Wout, out, BL_, D_, D_);
}

// Round 2
// 579.414 us; speedup vs baseline: 1.4453x; 1.4453x over previous
//
#include <hip/hip_runtime.h>
#include <hip/hip_bf16.h>
#include <math.h>

#define B_ 2
#define L_ 2048
#define D_ 1024
#define K_ 32
#define M_ 4
#define H_ 32
#define AH_ 4
#define DH_ 28
#define CK_ 4
#define TOTAL_ 2208
#define NPAD_ 2304
#define BL_ (B_*L_)
#define CL_ 64
#define NC_ (L_/CL_)

typedef __attribute__((ext_vector_type(8))) short bf16x8;
typedef __attribute__((ext_vector_type(4))) float f32x4;

static __device__ inline unsigned short f2bu(float f) {
    union { __hip_bfloat16 h; unsigned short u; } cv;
    cv.h = __float2bfloat16(f);
    return cv.u;
}
static __device__ inline float b2f(unsigned short u) {
    union { unsigned short u; __hip_bfloat16 h; } cv;
    cv.u = u;
    return __bfloat162float(cv.h);
}

// ---------- x -> bf16 ----------
__global__ void convert_x(const float4* __restrict__ src, ushort* __restrict__ dst) {
    int i = blockIdx.x * 256 + threadIdx.x;   // 1048576 total
    float4 v = src[i];
    ushort4 o;
    o.x = f2bu(v.x); o.y = f2bu(v.y); o.z = f2bu(v.z); o.w = f2bu(v.w);
    *(ushort4*)(dst + (size_t)i * 4) = o;
}

// ---------- transpose fp32 [K][N] -> bf16 [Npad][K] (zero-pad rows >= N) ----
__global__ void transpose_bf16_pad(const float* __restrict__ src, ushort* __restrict__ dst,
                                   int K, int N) {
    __shared__ float tile[64][65];
    int n0 = blockIdx.x * 64, k0 = blockIdx.y * 64;
    int t = threadIdx.x;
#pragma unroll
    for (int i = 0; i < 16; ++i) {
        int idx = t + i * 256;
        int r = idx >> 6, c = idx & 63;
        int gn = n0 + c;
        tile[r][c] = (gn < N) ? src[(size_t)(k0 + r) * N + gn] : 0.f;
    }
    __syncthreads();
#pragma unroll
    for (int i = 0; i < 16; ++i) {
        int idx = t + i * 256;
        int r = idx >> 6, c = idx & 63;   // r: n-offset, c: k-offset
        dst[(size_t)(n0 + r) * K + k0 + c] = f2bu(tile[c][r]);
    }
}

// ---------- W_out [1024][1024] -> split bf16 [1024 n][2048 k] (hi | lo) ------
__global__ void transpose_wout(const float* __restrict__ src, ushort* __restrict__ dst) {
    __shared__ float tile[64][65];
    int n0 = blockIdx.x * 64, k0 = blockIdx.y * 64;
    int t = threadIdx.x;
#pragma unroll
    for (int i = 0; i < 16; ++i) {
        int idx = t + i * 256;
        int r = idx >> 6, c = idx & 63;
        tile[r][c] = src[(size_t)(k0 + r) * 1024 + n0 + c];
    }
    __syncthreads();
#pragma unroll
    for (int i = 0; i < 16; ++i) {
        int idx = t + i * 256;
        int r = idx >> 6, c = idx & 63;
        float v = tile[c][r];
        unsigned short hi = f2bu(v);
        float lo = v - b2f(hi);
        size_t o = (size_t)(n0 + r) * 2048 + k0 + c;
        dst[o] = hi;
        dst[o + 1024] = f2bu(lo);
    }
}

// ---------- bf16 MFMA GEMM: C[M,N] = A[M,Kd] @ Bt[N,Kd]^T, C fp32 ------------
// tile 128x128, BK=32, 4 waves (2x2), each wave 64x64 via 4x4 16x16x32 MFMAs.
// XOR-swizzled LDS (slot = row*4 + (q ^ (row&3))) to keep ds_read_b128 2-way.
__global__ __launch_bounds__(256) void gemm_bt(const ushort* __restrict__ A,
                                               const ushort* __restrict__ Bt,
                                               float* __restrict__ C,
                                               int Kd, int ldc) {
    __shared__ __align__(16) ushort As[128 * 32];
    __shared__ __align__(16) ushort Bs[128 * 32];
    int tid = threadIdx.x;
    int wave = tid >> 6, lane = tid & 63;
    int quad = lane >> 4, l16 = lane & 15;
    int m0 = blockIdx.y * 128, n0 = blockIdx.x * 128;
    int wm = (wave >> 1) * 64, wn = (wave & 1) * 64;
    f32x4 acc[4][4];
#pragma unroll
    for (int i = 0; i < 4; ++i)
#pragma unroll
        for (int j = 0; j < 4; ++j) acc[i][j] = (f32x4){0.f, 0.f, 0.f, 0.f};

    int swzq = quad ^ (l16 & 3);   // swizzled quad for frag reads

    for (int k0 = 0; k0 < Kd; k0 += 32) {
#pragma unroll
        for (int i = 0; i < 2; ++i) {
            int s = i * 256 + tid;            // lds 16B-slot
            int row = s >> 2;
            int qg = (s & 3) ^ (row & 3);     // global col-quad for this slot
            const ushort* ga = A + (size_t)(m0 + row) * Kd + k0 + qg * 8;
            const ushort* gb = Bt + (size_t)(n0 + row) * Kd + k0 + qg * 8;
            __builtin_amdgcn_global_load_lds((const __attribute__((address_space(1))) void*)ga,
                                             (__attribute__((address_space(3))) void*)(As + (size_t)s * 8),
                                             16, 0, 0);
            __builtin_amdgcn_global_load_lds((const __attribute__((address_space(1))) void*)gb,
                                             (__attribute__((address_space(3))) void*)(Bs + (size_t)s * 8),
                                             16, 0, 0);
        }
        __syncthreads();
        bf16x8 af[4], bf[4];
#pragma unroll
        for (int mi = 0; mi < 4; ++mi) {
            int mr = wm + mi * 16 + l16;
            af[mi] = *(const bf16x8*)(As + (size_t)mr * 32 + swzq * 8);
        }
#pragma unroll
        for (int ni = 0; ni < 4; ++ni) {
            int nr = wn + ni * 16 + l16;
            bf[ni] = *(const bf16x8*)(Bs + (size_t)nr * 32 + swzq * 8);
        }
#pragma unroll
        for (int mi = 0; mi < 4; ++mi)
#pragma unroll
            for (int ni = 0; ni < 4; ++ni)
                acc[mi][ni] = __builtin_amdgcn_mfma_f32_16x16x32_bf16(af[mi], bf[ni], acc[mi][ni], 0, 0, 0);
        __syncthreads();
    }
#pragma unroll
    for (int mi = 0; mi < 4; ++mi)
#pragma unroll
        for (int ni = 0; ni < 4; ++ni)
#pragma unroll
            for (int r = 0; r < 4; ++r) {
                int gm = m0 + wm + mi * 16 + quad * 4 + r;
                int gn = n0 + wn + ni * 16 + l16;
                C[(size_t)gm * ldc + gn] = acc[mi][ni][r];
            }
}

// ---------- causal depthwise conv (z has row stride NPAD_) -------------------
__global__ void conv_kernel(const float* __restrict__ z, const float* __restrict__ cw,
                            const float* __restrict__ cb, float* __restrict__ zc) {
    int idx = blockIdx.x * 256 + threadIdx.x;
    if (idx >= BL_ * TOTAL_) return;
    int c = idx % TOTAL_;
    int bl = idx / TOTAL_;
    int l = bl % L_;
    float acc = cb[c];
#pragma unroll
    for (int t = 0; t < CK_; ++t) {
        int ls = l - (CK_ - 1) + t;
        if (ls >= 0) acc += z[(size_t)(bl - (CK_ - 1) + t) * NPAD_ + c] * cw[t * TOTAL_ + c];
    }
    zc[idx] = acc;
}

// ---------- scan pass 1: per-chunk sums --------------------------------------
__global__ __launch_bounds__(128) void pass1(const float* __restrict__ zc,
                                             const float* __restrict__ mask,
                                             const float* __restrict__ theta_base,
                                             const float* __restrict__ trs_,
                                             const float* __restrict__ dslopes,
                                             const float* __restrict__ aslopes,
                                             const float* __restrict__ sscale_,
                                             float* __restrict__ cs_re,
                                             float* __restrict__ cs_im,
                                             float* __restrict__ cs_den) {
    int nc = blockIdx.x, k = blockIdx.y, b = blockIdx.z;
    int hm = threadIdx.x;
    int h = hm >> 2, m = hm & 3;
    float raw = (k < DH_) ? dslopes[k] : aslopes[k - DH_];
    float slope = log1pf(expf(raw));
    float sscale = sscale_[k];
    float trs = trs_[k];
    float tb = theta_base[k * M_ + m];
    const float PI3 = 1.04719755119659775f;
    float acc_re = 0.f, acc_im = 0.f, acc_den = 0.f;
    int l0 = nc * CL_;
    for (int i = 0; i < CL_; ++i) {
        int l = l0 + i;
        size_t rowz = (size_t)(b * L_ + l) * TOTAL_;
        float mval = mask[b * L_ + l];
        float s_raw = zc[rowz + 2 * D_ + k] * mval;
        float tr = zc[rowz + 2 * D_ + K_ + k * M_ + m];
        float xv = zc[rowz + k * H_ + h] * mval;
        float arg = fminf(fmaxf(sscale * s_raw, -20.f), 20.f);
        float p = expf(arg) * mval;
        float tw = (k < DH_) ? expf(-slope * (float)(L_ - 1 - l)) : expf(-slope * (float)l);
        float pw = p * tw;
        float td = tr / (1.f + fabsf(tr));
        float theta = tb + trs * (td * PI3);
        float sv, cv;
        sincosf(xv * theta, &sv, &cv);
        acc_re += pw * cv;
        acc_im += pw * sv;
        acc_den += pw;
    }
    size_t o = ((size_t)((b * K_ + k) * NC_ + nc)) * 128 + hm;
    cs_re[o] = acc_re;
    cs_im[o] = acc_im;
    if (hm == 0) cs_den[(b * K_ + k) * NC_ + nc] = acc_den;
}

// ---------- scan pass 2: exclusive scan of chunk sums ------------------------
__global__ void pass2(float* cs_re, float* cs_im, float* cs_den) {
    int seq = blockIdx.x * 256 + threadIdx.x;
    if (seq >= B_ * K_ * 257) return;
    int bk = seq / 257;
    int ch = seq % 257;
    float* base;
    int stride;
    if (ch < 128) { base = cs_re + (size_t)bk * NC_ * 128 + ch; stride = 128; }
    else if (ch < 256) { base = cs_im + (size_t)bk * NC_ * 128 + (ch - 128); stride = 128; }
    else { base = cs_den + (size_t)bk * NC_; stride = 1; }
    float run = 0.f;
    for (int i = 0; i < NC_; ++i) {
        float v = base[(size_t)i * stride];
        base[(size_t)i * stride] = run;
        run += v;
    }
}

// ---------- scan pass 3: replay + norm + shfl matvec + gate → g' (hi|lo bf16)
__global__ __launch_bounds__(128) void pass3(const float* __restrict__ zc,
                                             const float* __restrict__ mask,
                                             const float* __restrict__ theta_base,
                                             const float* __restrict__ trs_,
                                             const float* __restrict__ dslopes,
                                             const float* __restrict__ aslopes,
                                             const float* __restrict__ sscale_,
                                             const float* __restrict__ nscale,
                                             const float* __restrict__ Wre,
                                             const float* __restrict__ Wim,
                                             const float* __restrict__ cs_re,
                                             const float* __restrict__ cs_im,
                                             const float* __restrict__ cs_den,
                                             ushort* __restrict__ gq) {
    __shared__ float s_red[2];
    __shared__ float s_part[64];
    int nc = blockIdx.x, k = blockIdx.y, b = blockIdx.z;
    int tid = threadIdx.x;
    int hm = tid;
    int h = hm >> 2, m = hm & 3;
    int lane = tid & 63, wid = tid >> 6;
    int part = tid >> 5;
    int hout = tid & 31;

    // register-resident folded weights: wre[q] = ns_re[hm2]*Wre[hm2][hout]
    float wre[32], wim[32];
#pragma unroll 8
    for (int q = 0; q < 32; ++q) {
        int hm2 = part * 32 + q;
        wre[q] = nscale[hm2] * Wre[hm2 * 32 + hout];
        wim[q] = nscale[128 + hm2] * Wim[hm2 * 32 + hout];
    }

    float raw = (k < DH_) ? dslopes[k] : aslopes[k - DH_];
    float slope = log1pf(expf(raw));
    float sscale = sscale_[k];
    float trs = trs_[k];
    float tb = theta_base[k * M_ + m];
    const float PI3 = 1.04719755119659775f;

    size_t o = ((size_t)((b * K_ + k) * NC_ + nc)) * 128 + hm;
    float acc_re = cs_re[o];
    float acc_im = cs_im[o];
    float den = cs_den[(b * K_ + k) * NC_ + nc];

    int l0 = nc * CL_;
    int shbase = (part & 1) << 5;
    for (int i = 0; i < CL_; ++i) {
        int l = l0 + i;
        size_t rowz = (size_t)(b * L_ + l) * TOTAL_;
        float mval = mask[b * L_ + l];
        float s_raw = zc[rowz + 2 * D_ + k] * mval;
        float tr = zc[rowz + 2 * D_ + K_ + k * M_ + m];
        float xv = zc[rowz + k * H_ + h] * mval;
        float arg = fminf(fmaxf(sscale * s_raw, -20.f), 20.f);
        float p = expf(arg) * mval;
        float tw = (k < DH_) ? expf(-slope * (float)(L_ - 1 - l)) : expf(-slope * (float)l);
        float pw = p * tw;
        float td = tr / (1.f + fabsf(tr));
        float theta = tb + trs * (td * PI3);
        float sv, cv;
        sincosf(xv * theta, &sv, &cv);
        acc_re += pw * cv;
        acc_im += pw * sv;
        den += pw;

        float inv = 1.f / fmaxf(den, 1e-4f);
        float re = acc_re * inv;
        float im = acc_im * inv;
        float v = re * re + im * im;
#pragma unroll
        for (int off = 32; off; off >>= 1) v += __shfl_xor(v, off, 64);
        if (lane == 0) s_red[wid] = v;
        __syncthreads();
        float rsq = rsqrtf((s_red[0] + s_red[1]) * (1.0f / 256.0f) + 1e-5f);
        float rn = re * rsq;
        float in_ = im * rsq;
        float sum = 0.f;
#pragma unroll
        for (int q = 0; q < 32; ++q) {
            sum = fmaf(__shfl(rn, shbase + q, 64), wre[q], sum);
            sum = fmaf(__shfl(in_, shbase + q, 64), wim[q], sum);
        }
        sum += __shfl_xor(sum, 32, 64);
        if (lane < 32) s_part[wid * 32 + lane] = sum;
        __syncthreads();
        if (tid < 32) {
            float y = s_part[tid] + s_part[32 + tid];
            float zg = zc[rowz + D_ + k * H_ + tid];
            float gate = zg / (1.f + expf(-zg));
            float gv = y * gate;
            unsigned short hi = f2bu(gv);
            float lov = gv - b2f(hi);
            size_t go = (size_t)(b * L_ + l) * 2048 + k * H_ + tid;
            gq[go] = hi;
            gq[go + 1024] = f2bu(lov);
        }
    }
}

extern "C" void kernel_launch(void* const* d_in, const int* in_sizes, int n_in,
                              void* d_out, int out_size, void* d_ws, size_t ws_size,
                              hipStream_t stream) {
    const float* x = (const float*)d_in[0];
    const float* mask = (const float*)d_in[1];
    const float* W_in = (const float*)d_in[2];
    const float* conv_w = (const float*)d_in[3];
    const float* conv_b = (const float*)d_in[4];
    const float* theta_base = (const float*)d_in[5];
    const float* trs = (const float*)d_in[6];
    const float* dsl = (const float*)d_in[7];
    const float* asl = (const float*)d_in[8];
    const float* ssc = (const float*)d_in[9];
    const float* nsc = (const float*)d_in[10];
    const float* Wre = (const float*)d_in[11];
    const float* Wim = (const float*)d_in[12];
    const float* Wout = (const float*)d_in[13];
    float* out = (float*)d_out;

    char* ws = (char*)d_ws;
    float* zc    = (float*)(ws);                    // 36,175,872
    float* z     = (float*)(ws + 36175872ULL);      // 4096*2304*4 = 37,748,736
    ushort* x_bf = (ushort*)(ws + 73924608ULL);     // 8,388,608
    ushort* Wt_in = (ushort*)(ws + 82313216ULL);    // 2304*1024*2 = 4,718,592
    ushort* Wt_o2 = (ushort*)(ws + 87031808ULL);    // 1024*2048*2 = 4,194,304
    ushort* gq   = (ushort*)(ws + 91226112ULL);     // 4096*2048*2 = 16,777,216
    float* cs_re = (float*)(ws + 108003328ULL);     // 1,048,576
    float* cs_im = (float*)(ws + 109051904ULL);     // 1,048,576
    float* cs_den = (float*)(ws + 110100480ULL);    // 8,192

    convert_x<<<4096, 256, 0, stream>>>((const float4*)x, x_bf);
    transpose_bf16_pad<<<dim3(NPAD_ / 64, 16), 256, 0, stream>>>(W_in, Wt_in, 1024, TOTAL_);
    transpose_wout<<<dim3(16, 16), 256, 0, stream>>>(Wout, Wt_o2);
    gemm_bt<<<dim3(NPAD_ / 128, BL_ / 128), 256, 0, stream>>>(x_bf, Wt_in, z, 1024, NPAD_);
    conv_kernel<<<(BL_ * TOTAL_ + 255) / 256, 256, 0, stream>>>(z, conv_w, conv_b, zc);
    pass1<<<dim3(NC_, K_, B_), 128, 0, stream>>>(zc, mask, theta_base, trs, dsl, asl, ssc,
                                                 cs_re, cs_im, cs_den);
    pass2<<<(B_ * K_ * 257 + 255) / 256, 256, 0, stream>>>(cs_re, cs_im, cs_den);
    pass3<<<dim3(NC_, K_, B_), 128, 0, stream>>>(zc, mask, theta_base, trs, dsl, asl, ssc,
                                                 nsc, Wre, Wim, cs_re, cs_im, cs_den, gq);
    gemm_bt<<<dim3(1024 / 128, BL_ / 128), 256, 0, stream>>>(gq, Wt_o2, out, 2048, 1024);
}

// Round 3
// 400.160 us; speedup vs baseline: 2.0927x; 1.4480x over previous
//
#include <hip/hip_runtime.h>
#include <hip/hip_bf16.h>
#include <math.h>

#define B_ 2
#define L_ 2048
#define D_ 1024
#define K_ 32
#define M_ 4
#define H_ 32
#define AH_ 4
#define DH_ 28
#define CK_ 4
#define TOTAL_ 2208
#define NPAD_ 2304
#define BL_ (B_*L_)
#define CL_ 64
#define NC_ (L_/CL_)
#define CTS_ 280   // c_tile row stride in ushorts (560 B: 16B-aligned, 2-way banks)

typedef __attribute__((ext_vector_type(8))) short bf16x8;
typedef __attribute__((ext_vector_type(4))) float f32x4;

static __device__ inline unsigned short f2bu(float f) {
    union { __hip_bfloat16 h; unsigned short u; } cv;
    cv.h = __float2bfloat16(f);
    return cv.u;
}
static __device__ inline float b2f(unsigned short u) {
    union { unsigned short u; __hip_bfloat16 h; } cv;
    cv.u = u;
    return __bfloat162float(cv.h);
}

// ---------- x -> bf16 ----------
__global__ void convert_x(const float4* __restrict__ src, ushort* __restrict__ dst) {
    int i = blockIdx.x * 256 + threadIdx.x;
    float4 v = src[i];
    ushort4 o;
    o.x = f2bu(v.x); o.y = f2bu(v.y); o.z = f2bu(v.z); o.w = f2bu(v.w);
    *(ushort4*)(dst + (size_t)i * 4) = o;
}

// ---------- transpose fp32 [K][N] -> bf16 [Npad][K] (zero-pad rows >= N) ----
__global__ void transpose_bf16_pad(const float* __restrict__ src, ushort* __restrict__ dst,
                                   int K, int N) {
    __shared__ float tile[64][65];
    int n0 = blockIdx.x * 64, k0 = blockIdx.y * 64;
    int t = threadIdx.x;
#pragma unroll
    for (int i = 0; i < 16; ++i) {
        int idx = t + i * 256;
        int r = idx >> 6, c = idx & 63;
        int gn = n0 + c;
        tile[r][c] = (gn < N) ? src[(size_t)(k0 + r) * N + gn] : 0.f;
    }
    __syncthreads();
#pragma unroll
    for (int i = 0; i < 16; ++i) {
        int idx = t + i * 256;
        int r = idx >> 6, c = idx & 63;
        dst[(size_t)(n0 + r) * K + k0 + c] = f2bu(tile[c][r]);
    }
}

// ---------- W'' prep: W2B[hout][ch] = nscale[ch] * (ch<128 ? Wre : Wim) -----
__global__ void prep_w2(const float* __restrict__ Wre, const float* __restrict__ Wim,
                        const float* __restrict__ nscale, ushort* __restrict__ W2B) {
    int ch = threadIdx.x;  // 256
    float ns = nscale[ch];
    for (int hout = 0; hout < 32; ++hout) {
        float w = (ch < 128) ? Wre[ch * 32 + hout] : Wim[(ch - 128) * 32 + hout];
        W2B[hout * 256 + ch] = f2bu(ns * w);
    }
}

// ---------- bf16 MFMA GEMM: C[M,N] = A[M,Kd] @ Bt[N,Kd]^T, C fp32 ------------
__global__ __launch_bounds__(256) void gemm_bt(const ushort* __restrict__ A,
                                               const ushort* __restrict__ Bt,
                                               float* __restrict__ C,
                                               int Kd, int ldc) {
    __shared__ __align__(16) ushort As[128 * 32];
    __shared__ __align__(16) ushort Bs[128 * 32];
    int tid = threadIdx.x;
    int wave = tid >> 6, lane = tid & 63;
    int quad = lane >> 4, l16 = lane & 15;
    int m0 = blockIdx.y * 128, n0 = blockIdx.x * 128;
    int wm = (wave >> 1) * 64, wn = (wave & 1) * 64;
    f32x4 acc[4][4];
#pragma unroll
    for (int i = 0; i < 4; ++i)
#pragma unroll
        for (int j = 0; j < 4; ++j) acc[i][j] = (f32x4){0.f, 0.f, 0.f, 0.f};

    int swzq = quad ^ (l16 & 3);

    for (int k0 = 0; k0 < Kd; k0 += 32) {
#pragma unroll
        for (int i = 0; i < 2; ++i) {
            int s = i * 256 + tid;
            int row = s >> 2;
            int qg = (s & 3) ^ (row & 3);
            const ushort* ga = A + (size_t)(m0 + row) * Kd + k0 + qg * 8;
            const ushort* gb = Bt + (size_t)(n0 + row) * Kd + k0 + qg * 8;
            __builtin_amdgcn_global_load_lds((const __attribute__((address_space(1))) void*)ga,
                                             (__attribute__((address_space(3))) void*)(As + (size_t)s * 8),
                                             16, 0, 0);
            __builtin_amdgcn_global_load_lds((const __attribute__((address_space(1))) void*)gb,
                                             (__attribute__((address_space(3))) void*)(Bs + (size_t)s * 8),
                                             16, 0, 0);
        }
        __syncthreads();
        bf16x8 af[4], bfr[4];
#pragma unroll
        for (int mi = 0; mi < 4; ++mi)
            af[mi] = *(const bf16x8*)(As + (size_t)(wm + mi * 16 + l16) * 32 + swzq * 8);
#pragma unroll
        for (int ni = 0; ni < 4; ++ni)
            bfr[ni] = *(const bf16x8*)(Bs + (size_t)(wn + ni * 16 + l16) * 32 + swzq * 8);
#pragma unroll
        for (int mi = 0; mi < 4; ++mi)
#pragma unroll
            for (int ni = 0; ni < 4; ++ni)
                acc[mi][ni] = __builtin_amdgcn_mfma_f32_16x16x32_bf16(af[mi], bfr[ni], acc[mi][ni], 0, 0, 0);
        __syncthreads();
    }
#pragma unroll
    for (int mi = 0; mi < 4; ++mi)
#pragma unroll
        for (int ni = 0; ni < 4; ++ni)
#pragma unroll
            for (int r = 0; r < 4; ++r) {
                int gm = m0 + wm + mi * 16 + quad * 4 + r;
                int gn = n0 + wn + ni * 16 + l16;
                C[(size_t)gm * ldc + gn] = acc[mi][ni][r];
            }
}

// ---------- causal depthwise conv (z row stride NPAD_) -----------------------
__global__ void conv_kernel(const float* __restrict__ z, const float* __restrict__ cw,
                            const float* __restrict__ cb, float* __restrict__ zc) {
    int idx = blockIdx.x * 256 + threadIdx.x;
    if (idx >= BL_ * TOTAL_) return;
    int c = idx % TOTAL_;
    int bl = idx / TOTAL_;
    int l = bl % L_;
    float acc = cb[c];
#pragma unroll
    for (int t = 0; t < CK_; ++t) {
        int ls = l - (CK_ - 1) + t;
        if (ls >= 0) acc += z[(size_t)(bl - (CK_ - 1) + t) * NPAD_ + c] * cw[t * TOTAL_ + c];
    }
    zc[idx] = acc;
}

// ---------- pass1: chunk sums + contributions -> LDS -> vc via MFMA ----------
__global__ __launch_bounds__(128) void pass1(const float* __restrict__ zc,
                                             const float* __restrict__ mask,
                                             const float* __restrict__ theta_base,
                                             const float* __restrict__ trs_,
                                             const float* __restrict__ dslopes,
                                             const float* __restrict__ aslopes,
                                             const float* __restrict__ sscale_,
                                             const ushort* __restrict__ W2B,
                                             float* __restrict__ cs_re,
                                             float* __restrict__ cs_im,
                                             float* __restrict__ cs_den,
                                             float* __restrict__ vc) {
    __shared__ __align__(16) ushort ct[64 * CTS_];
    int nc = blockIdx.x, k = blockIdx.y, b = blockIdx.z;
    int hm = threadIdx.x;
    int h = hm >> 2, m = hm & 3;
    float raw = (k < DH_) ? dslopes[k] : aslopes[k - DH_];
    float slope = log1pf(__expf(raw));
    float sscale = sscale_[k];
    float trsv = trs_[k];
    float tb = theta_base[k * M_ + m];
    const float PI3 = 1.04719755119659775f;
    float are = 0.f, aim = 0.f, aden = 0.f;
    int l0 = nc * CL_;
    for (int i = 0; i < CL_; ++i) {
        int l = l0 + i;
        size_t rowz = (size_t)(b * L_ + l) * TOTAL_;
        float mval = mask[b * L_ + l];
        float s_raw = zc[rowz + 2 * D_ + k] * mval;
        float tr = zc[rowz + 2 * D_ + K_ + k * M_ + m];
        float xv = zc[rowz + k * H_ + h] * mval;
        float arg = fminf(fmaxf(sscale * s_raw, -20.f), 20.f);
        float p = __expf(arg) * mval;
        float tw = (k < DH_) ? __expf(-slope * (float)(L_ - 1 - l)) : __expf(-slope * (float)l);
        float pw = p * tw;
        float td = tr / (1.f + fabsf(tr));
        float theta = tb + trsv * (td * PI3);
        float phi = xv * theta;
        float sv = __sinf(phi), cv = __cosf(phi);
        float cre = pw * cv, cim = pw * sv;
        are += cre; aim += cim; aden += pw;
        ct[i * CTS_ + hm] = f2bu(cre);
        ct[i * CTS_ + 128 + hm] = f2bu(cim);
    }
    size_t o = ((size_t)((b * K_ + k) * NC_ + nc)) * 128 + hm;
    cs_re[o] = are;
    cs_im[o] = aim;
    if (hm == 0) cs_den[(b * K_ + k) * NC_ + nc] = aden;
    __syncthreads();
    // phase B: vc[l, hout] = C_chunk(64x256) @ W''(256x32) via MFMA
    int wave = hm >> 6, lane = hm & 63;
    int quad = lane >> 4, l16 = lane & 15;
    f32x4 acc[2][2];
#pragma unroll
    for (int t = 0; t < 2; ++t)
#pragma unroll
        for (int nt = 0; nt < 2; ++nt) acc[t][nt] = (f32x4){0.f, 0.f, 0.f, 0.f};
#pragma unroll
    for (int ks = 0; ks < 8; ++ks) {
        bf16x8 af[2], bfr[2];
#pragma unroll
        for (int t = 0; t < 2; ++t) {
            int mt = wave * 2 + t;
            af[t] = *(const bf16x8*)(ct + (size_t)(mt * 16 + l16) * CTS_ + ks * 32 + quad * 8);
        }
#pragma unroll
        for (int nt = 0; nt < 2; ++nt)
            bfr[nt] = *(const bf16x8*)(W2B + (size_t)(nt * 16 + l16) * 256 + ks * 32 + quad * 8);
#pragma unroll
        for (int t = 0; t < 2; ++t)
#pragma unroll
            for (int nt = 0; nt < 2; ++nt)
                acc[t][nt] = __builtin_amdgcn_mfma_f32_16x16x32_bf16(af[t], bfr[nt], acc[t][nt], 0, 0, 0);
    }
    size_t vbase = ((size_t)(b * K_ + k) * L_ + l0) * 32;
#pragma unroll
    for (int t = 0; t < 2; ++t)
#pragma unroll
        for (int nt = 0; nt < 2; ++nt)
#pragma unroll
            for (int r = 0; r < 4; ++r) {
                int row = wave * 32 + t * 16 + quad * 4 + r;
                vc[vbase + (size_t)row * 32 + nt * 16 + l16] = acc[t][nt][r];
            }
}

// ---------- pass2: exclusive scan of chunk sums ------------------------------
__global__ void pass2(float* cs_re, float* cs_im, float* cs_den) {
    int seq = blockIdx.x * 256 + threadIdx.x;
    if (seq >= B_ * K_ * 257) return;
    int bk = seq / 257;
    int ch = seq % 257;
    float* base;
    int stride;
    if (ch < 128) { base = cs_re + (size_t)bk * NC_ * 128 + ch; stride = 128; }
    else if (ch < 256) { base = cs_im + (size_t)bk * NC_ * 128 + (ch - 128); stride = 128; }
    else { base = cs_den + (size_t)bk * NC_; stride = 1; }
    float run = 0.f;
    for (int i = 0; i < NC_; ++i) {
        float v = base[(size_t)i * stride];
        base[(size_t)i * stride] = run;
        run += v;
    }
}

// ---------- u_prev = A_prev @ W'' (carry matvec) -----------------------------
__global__ __launch_bounds__(64) void uprev_mv(const float* __restrict__ cs_re,
                                               const float* __restrict__ cs_im,
                                               const ushort* __restrict__ W2B,
                                               float* __restrict__ u_prev) {
    int nc = blockIdx.x, k = blockIdx.y, b = blockIdx.z;
    int lane = threadIdx.x;
    int hout = lane & 31, half = lane >> 5;
    size_t base = ((size_t)((b * K_ + k) * NC_ + nc)) * 128;
    const float* src = half ? cs_im : cs_re;
    int choff = half * 128;
    float sum = 0.f;
#pragma unroll 8
    for (int i = 0; i < 128; ++i) {
        float a = src[base + i];
        float w = b2f(W2B[hout * 256 + choff + i]);
        sum = fmaf(a, w, sum);
    }
    sum += __shfl_xor(sum, 32, 64);
    if (lane < 32) u_prev[((size_t)((b * K_ + k) * NC_ + nc)) * 32 + hout] = sum;
}

// ---------- scan: barrier-free per-chunk scan + prefix of vc + gate ----------
__global__ __launch_bounds__(64) void scan_kernel(const float* __restrict__ zc,
                                                  const float* __restrict__ mask,
                                                  const float* __restrict__ theta_base,
                                                  const float* __restrict__ trs_,
                                                  const float* __restrict__ dslopes,
                                                  const float* __restrict__ aslopes,
                                                  const float* __restrict__ sscale_,
                                                  const float* __restrict__ cs_re,
                                                  const float* __restrict__ cs_im,
                                                  const float* __restrict__ cs_den,
                                                  const float* __restrict__ u_prev,
                                                  const float* __restrict__ vc,
                                                  ushort* __restrict__ gq) {
    int nc = blockIdx.x, k = blockIdx.y, b = blockIdx.z;
    int lane = threadIdx.x;
    int bk = b * K_ + k;
    int h0 = lane >> 2, h1 = 16 + (lane >> 2), m = lane & 3;
    float raw = (k < DH_) ? dslopes[k] : aslopes[k - DH_];
    float slope = log1pf(__expf(raw));
    float sscale = sscale_[k];
    float trsv = trs_[k];
    float tb = theta_base[k * M_ + m];
    const float PI3 = 1.04719755119659775f;

    size_t o = ((size_t)(bk * NC_ + nc)) * 128;
    float are0 = cs_re[o + lane];
    float are1 = cs_re[o + 64 + lane];
    float aim0 = cs_im[o + lane];
    float aim1 = cs_im[o + 64 + lane];
    float den = cs_den[bk * NC_ + nc];
    float sc_keep = 0.f;
    int l0 = nc * CL_;

    for (int i = 0; i < CL_; ++i) {
        int l = l0 + i;
        int row = b * L_ + l;
        size_t rowz = (size_t)row * TOTAL_;
        float mval = mask[row];
        float s_raw = zc[rowz + 2 * D_ + k] * mval;
        float tr = zc[rowz + 2 * D_ + K_ + k * M_ + m];
        float xv0 = zc[rowz + k * H_ + h0] * mval;
        float xv1 = zc[rowz + k * H_ + h1] * mval;
        float arg = fminf(fmaxf(sscale * s_raw, -20.f), 20.f);
        float p = __expf(arg) * mval;
        float tw = (k < DH_) ? __expf(-slope * (float)(L_ - 1 - l)) : __expf(-slope * (float)l);
        float pw = p * tw;
        float td = tr / (1.f + fabsf(tr));
        float theta = tb + trsv * (td * PI3);
        float s0 = __sinf(xv0 * theta), c0 = __cosf(xv0 * theta);
        float s1 = __sinf(xv1 * theta), c1 = __cosf(xv1 * theta);
        // bf16-round to match the vc path (error correlation)
        float cre0 = b2f(f2bu(pw * c0)), cim0 = b2f(f2bu(pw * s0));
        float cre1 = b2f(f2bu(pw * c1)), cim1 = b2f(f2bu(pw * s1));
        are0 += cre0; aim0 += cim0; are1 += cre1; aim1 += cim1;
        den += pw;
        float s = are0 * are0 + are1 * are1 + aim0 * aim0 + aim1 * aim1;
#pragma unroll
        for (int off = 32; off; off >>= 1) s += __shfl_xor(s, off, 64);
        float inv = 1.f / fmaxf(den, 1e-4f);
        float rsq = rsqrtf(inv * inv * s * (1.0f / 256.0f) + 1e-5f);
        float scv = inv * rsq;
        sc_keep = (lane == i) ? scv : sc_keep;
    }

    // epilogue: prefix of vc + gate (halves duplicate the u-chain; hi store by lanes<32)
    int hout = lane & 31;
    float u = u_prev[((size_t)(bk * NC_ + nc)) * 32 + hout];
    for (int i = 0; i < CL_; ++i) {
        int l = l0 + i;
        int row = b * L_ + l;
        u += vc[((size_t)bk * L_ + l) * 32 + hout];
        float y = __shfl(sc_keep, i, 64) * u;
        float zg = zc[(size_t)row * TOTAL_ + D_ + k * H_ + hout];
        float gate = zg / (1.f + __expf(-zg));
        float gv = y * gate;
        if (lane < 32) gq[(size_t)row * D_ + k * H_ + hout] = f2bu(gv);
    }
}

extern "C" void kernel_launch(void* const* d_in, const int* in_sizes, int n_in,
                              void* d_out, int out_size, void* d_ws, size_t ws_size,
                              hipStream_t stream) {
    const float* x = (const float*)d_in[0];
    const float* mask = (const float*)d_in[1];
    const float* W_in = (const float*)d_in[2];
    const float* conv_w = (const float*)d_in[3];
    const float* conv_b = (const float*)d_in[4];
    const float* theta_base = (const float*)d_in[5];
    const float* trs = (const float*)d_in[6];
    const float* dsl = (const float*)d_in[7];
    const float* asl = (const float*)d_in[8];
    const float* ssc = (const float*)d_in[9];
    const float* nsc = (const float*)d_in[10];
    const float* Wre = (const float*)d_in[11];
    const float* Wim = (const float*)d_in[12];
    const float* Wout = (const float*)d_in[13];
    float* out = (float*)d_out;

    char* ws = (char*)d_ws;
    float* zc     = (float*)(ws);                   // 36,175,872
    float* z      = (float*)(ws + 36175872ULL);     // 37,748,736 (vc aliases this)
    float* vc     = (float*)(ws + 36175872ULL);     // 16,777,216 (after conv consumes z)
    ushort* x_bf  = (ushort*)(ws + 73924608ULL);    // 8,388,608
    ushort* Wt_in = (ushort*)(ws + 82313216ULL);    // 4,718,592
    ushort* Wt_o  = (ushort*)(ws + 87031808ULL);    // 2,097,152
    ushort* gq    = (ushort*)(ws + 89128960ULL);    // 8,388,608
    float* cs_re  = (float*)(ws + 97517568ULL);     // 1,048,576
    float* cs_im  = (float*)(ws + 98566144ULL);     // 1,048,576
    float* cs_den = (float*)(ws + 99614720ULL);     // 8,192
    ushort* W2B   = (ushort*)(ws + 99622912ULL);    // 16,384
    float* u_prev = (float*)(ws + 99639296ULL);     // 262,144

    convert_x<<<4096, 256, 0, stream>>>((const float4*)x, x_bf);
    transpose_bf16_pad<<<dim3(NPAD_ / 64, 16), 256, 0, stream>>>(W_in, Wt_in, 1024, TOTAL_);
    transpose_bf16_pad<<<dim3(16, 16), 256, 0, stream>>>(Wout, Wt_o, 1024, 1024);
    prep_w2<<<1, 256, 0, stream>>>(Wre, Wim, nsc, W2B);
    gemm_bt<<<dim3(NPAD_ / 128, BL_ / 128), 256, 0, stream>>>(x_bf, Wt_in, z, 1024, NPAD_);
    conv_kernel<<<(BL_ * TOTAL_ + 255) / 256, 256, 0, stream>>>(z, conv_w, conv_b, zc);
    pass1<<<dim3(NC_, K_, B_), 128, 0, stream>>>(zc, mask, theta_base, trs, dsl, asl, ssc,
                                                 W2B, cs_re, cs_im, cs_den, vc);
    pass2<<<(B_ * K_ * 257 + 255) / 256, 256, 0, stream>>>(cs_re, cs_im, cs_den);
    uprev_mv<<<dim3(NC_, K_, B_), 64, 0, stream>>>(cs_re, cs_im, W2B, u_prev);
    scan_kernel<<<dim3(NC_, K_, B_), 64, 0, stream>>>(zc, mask, theta_base, trs, dsl, asl, ssc,
                                                      cs_re, cs_im, cs_den, u_prev, vc, gq);
    gemm_bt<<<dim3(D_ / 128, BL_ / 128), 256, 0, stream>>>(gq, Wt_o, out, 1024, 1024);
}

// Round 4
// 303.675 us; speedup vs baseline: 2.7576x; 1.3177x over previous
//
#include <hip/hip_runtime.h>
#include <hip/hip_bf16.h>
#include <math.h>

#define B_ 2
#define L_ 2048
#define D_ 1024
#define K_ 32
#define M_ 4
#define H_ 32
#define AH_ 4
#define DH_ 28
#define CK_ 4
#define TOTAL_ 2208
#define NPAD_ 2304
#define BL_ (B_*L_)
#define CL_ 32
#define NC_ (L_/CL_)
#define CTS_ 280   // ct row stride (ushorts)
#define ZS_ 72     // zck row stride (floats): xv 0-31, gate 32-63, s 64, pad, theta 68-71

typedef __attribute__((ext_vector_type(8))) short bf16x8;
typedef __attribute__((ext_vector_type(4))) float f32x4;

static __device__ inline unsigned short f2bu(float f) {
    union { __hip_bfloat16 h; unsigned short u; } cv;
    cv.h = __float2bfloat16(f);
    return cv.u;
}
static __device__ inline float b2f(unsigned short u) {
    union { unsigned short u; __hip_bfloat16 h; } cv;
    cv.u = u;
    return __bfloat162float(cv.h);
}

// ---------- x -> bf16 ----------
__global__ void convert_x(const float4* __restrict__ src, ushort* __restrict__ dst) {
    int i = blockIdx.x * 256 + threadIdx.x;
    float4 v = src[i];
    ushort4 o;
    o.x = f2bu(v.x); o.y = f2bu(v.y); o.z = f2bu(v.z); o.w = f2bu(v.w);
    *(ushort4*)(dst + (size_t)i * 4) = o;
}

// ---------- transpose fp32 [K][N] -> bf16 [Npad][K] (zero-pad rows >= N) ----
__global__ void transpose_bf16_pad(const float* __restrict__ src, ushort* __restrict__ dst,
                                   int K, int N) {
    __shared__ float tile[64][65];
    int n0 = blockIdx.x * 64, k0 = blockIdx.y * 64;
    int t = threadIdx.x;
#pragma unroll
    for (int i = 0; i < 16; ++i) {
        int idx = t + i * 256;
        int r = idx >> 6, c = idx & 63;
        int gn = n0 + c;
        tile[r][c] = (gn < N) ? src[(size_t)(k0 + r) * N + gn] : 0.f;
    }
    __syncthreads();
#pragma unroll
    for (int i = 0; i < 16; ++i) {
        int idx = t + i * 256;
        int r = idx >> 6, c = idx & 63;
        dst[(size_t)(n0 + r) * K + k0 + c] = f2bu(tile[c][r]);
    }
}

// ---------- W'' prep: W2B[hout][ch] = nscale[ch] * (ch<128 ? Wre : Wim) -----
__global__ void prep_w2(const float* __restrict__ Wre, const float* __restrict__ Wim,
                        const float* __restrict__ nscale, ushort* __restrict__ W2B) {
    int ch = threadIdx.x;  // 256
    float ns = nscale[ch];
    for (int hout = 0; hout < 32; ++hout) {
        float w = (ch < 128) ? Wre[ch * 32 + hout] : Wim[(ch - 128) * 32 + hout];
        W2B[hout * 256 + ch] = f2bu(ns * w);
    }
}

// ---------- bf16 MFMA GEMM: C[M,N] = A[M,Kd] @ Bt[N,Kd]^T, C fp32 ------------
__global__ __launch_bounds__(256) void gemm_bt(const ushort* __restrict__ A,
                                               const ushort* __restrict__ Bt,
                                               float* __restrict__ C,
                                               int Kd, int ldc) {
    __shared__ __align__(16) ushort As[128 * 32];
    __shared__ __align__(16) ushort Bs[128 * 32];
    int tid = threadIdx.x;
    int wave = tid >> 6, lane = tid & 63;
    int quad = lane >> 4, l16 = lane & 15;
    int m0 = blockIdx.y * 128, n0 = blockIdx.x * 128;
    int wm = (wave >> 1) * 64, wn = (wave & 1) * 64;
    f32x4 acc[4][4];
#pragma unroll
    for (int i = 0; i < 4; ++i)
#pragma unroll
        for (int j = 0; j < 4; ++j) acc[i][j] = (f32x4){0.f, 0.f, 0.f, 0.f};

    int swzq = quad ^ (l16 & 3);

    for (int k0 = 0; k0 < Kd; k0 += 32) {
#pragma unroll
        for (int i = 0; i < 2; ++i) {
            int s = i * 256 + tid;
            int row = s >> 2;
            int qg = (s & 3) ^ (row & 3);
            const ushort* ga = A + (size_t)(m0 + row) * Kd + k0 + qg * 8;
            const ushort* gb = Bt + (size_t)(n0 + row) * Kd + k0 + qg * 8;
            __builtin_amdgcn_global_load_lds((const __attribute__((address_space(1))) void*)ga,
                                             (__attribute__((address_space(3))) void*)(As + (size_t)s * 8),
                                             16, 0, 0);
            __builtin_amdgcn_global_load_lds((const __attribute__((address_space(1))) void*)gb,
                                             (__attribute__((address_space(3))) void*)(Bs + (size_t)s * 8),
                                             16, 0, 0);
        }
        __syncthreads();
        bf16x8 af[4], bfr[4];
#pragma unroll
        for (int mi = 0; mi < 4; ++mi)
            af[mi] = *(const bf16x8*)(As + (size_t)(wm + mi * 16 + l16) * 32 + swzq * 8);
#pragma unroll
        for (int ni = 0; ni < 4; ++ni)
            bfr[ni] = *(const bf16x8*)(Bs + (size_t)(wn + ni * 16 + l16) * 32 + swzq * 8);
#pragma unroll
        for (int mi = 0; mi < 4; ++mi)
#pragma unroll
            for (int ni = 0; ni < 4; ++ni)
                acc[mi][ni] = __builtin_amdgcn_mfma_f32_16x16x32_bf16(af[mi], bfr[ni], acc[mi][ni], 0, 0, 0);
        __syncthreads();
    }
#pragma unroll
    for (int mi = 0; mi < 4; ++mi)
#pragma unroll
        for (int ni = 0; ni < 4; ++ni)
#pragma unroll
            for (int r = 0; r < 4; ++r) {
                int gm = m0 + wm + mi * 16 + quad * 4 + r;
                int gn = n0 + wn + ni * 16 + l16;
                C[(size_t)gm * ldc + gn] = acc[mi][ni][r];
            }
}

// ---------- causal depthwise conv + K-major relayout -------------------------
// zck[b][k][l][ZS_]: slots 0-31 = x_val(h), 32-63 = gate pre-act, 64 = s_raw,
// 68-71 = theta_raw(m). Slots 65-67 unused.
__global__ void conv_kernel(const float* __restrict__ z, const float* __restrict__ cw,
                            const float* __restrict__ cb, float* __restrict__ zck) {
    int t = blockIdx.x * 256 + threadIdx.x;
    if (t >= BL_ * (TOTAL_ / 4)) return;
    int c4 = (t % (TOTAL_ / 4)) * 4;
    int bl = t / (TOTAL_ / 4);
    int l = bl % L_, b = bl / L_;
    float4 acc = *(const float4*)(cb + c4);
#pragma unroll
    for (int tap = 0; tap < CK_; ++tap) {
        int ls = l - (CK_ - 1) + tap;
        if (ls >= 0) {
            float4 zv = *(const float4*)(z + (size_t)(bl - (CK_ - 1) + tap) * NPAD_ + c4);
            float4 wv = *(const float4*)(cw + tap * TOTAL_ + c4);
            acc.x = fmaf(zv.x, wv.x, acc.x);
            acc.y = fmaf(zv.y, wv.y, acc.y);
            acc.z = fmaf(zv.z, wv.z, acc.z);
            acc.w = fmaf(zv.w, wv.w, acc.w);
        }
    }
    if (c4 < D_) {
        int k = c4 >> 5, slot = c4 & 31;
        *(float4*)(zck + ((size_t)(b * K_ + k) * L_ + l) * ZS_ + slot) = acc;
    } else if (c4 < 2 * D_) {
        int cc = c4 - D_;
        int k = cc >> 5, slot = 32 + (cc & 31);
        *(float4*)(zck + ((size_t)(b * K_ + k) * L_ + l) * ZS_ + slot) = acc;
    } else if (c4 < 2 * D_ + K_) {
        float av[4] = {acc.x, acc.y, acc.z, acc.w};
#pragma unroll
        for (int q = 0; q < 4; ++q) {
            int k = c4 + q - 2 * D_;
            zck[((size_t)(b * K_ + k) * L_ + l) * ZS_ + 64] = av[q];
        }
    } else {
        int j = c4 - (2 * D_ + K_);
        int k = j >> 2;
        *(float4*)(zck + ((size_t)(b * K_ + k) * L_ + l) * ZS_ + 68) = acc;
    }
}

// ---------- pass1: chunk sums + contributions -> LDS -> vc via MFMA ----------
__global__ __launch_bounds__(128) void pass1(const float* __restrict__ zck,
                                             const float* __restrict__ mask,
                                             const float* __restrict__ theta_base,
                                             const float* __restrict__ trs_,
                                             const float* __restrict__ dslopes,
                                             const float* __restrict__ aslopes,
                                             const float* __restrict__ sscale_,
                                             const ushort* __restrict__ W2B,
                                             float* __restrict__ cs_re,
                                             float* __restrict__ cs_im,
                                             float* __restrict__ cs_den,
                                             float* __restrict__ vc) {
    __shared__ __align__(16) ushort ct[CL_ * CTS_];
    int nc = blockIdx.x, k = blockIdx.y, b = blockIdx.z;
    int hm = threadIdx.x;
    int h = hm >> 2, m = hm & 3;
    int bk = b * K_ + k;
    size_t bkL = (size_t)bk * L_;
    float raw = (k < DH_) ? dslopes[k] : aslopes[k - DH_];
    float slope = log1pf(__expf(raw));
    float sscale = sscale_[k];
    float trsv = trs_[k];
    float tb = theta_base[k * M_ + m];
    const float PI3 = 1.04719755119659775f;
    float are = 0.f, aim = 0.f, aden = 0.f;
    int l0 = nc * CL_;
#pragma unroll 4
    for (int i = 0; i < CL_; ++i) {
        int l = l0 + i;
        const float* zrow = zck + (bkL + l) * ZS_;
        float mval = mask[b * L_ + l];
        float s_raw = zrow[64] * mval;
        float tr = zrow[68 + m];
        float xv = zrow[h] * mval;
        float arg = fminf(fmaxf(sscale * s_raw, -20.f), 20.f);
        float p = __expf(arg) * mval;
        float tw = (k < DH_) ? __expf(-slope * (float)(L_ - 1 - l)) : __expf(-slope * (float)l);
        float pw = p * tw;
        float td = tr / (1.f + fabsf(tr));
        float theta = tb + trsv * (td * PI3);
        float phi = xv * theta;
        float sv = __sinf(phi), cv = __cosf(phi);
        unsigned short cu_re = f2bu(pw * cv);
        unsigned short cu_im = f2bu(pw * sv);
        are += b2f(cu_re); aim += b2f(cu_im); aden += pw;
        ct[i * CTS_ + hm] = cu_re;
        ct[i * CTS_ + 128 + hm] = cu_im;
    }
    size_t o = ((size_t)(bk * NC_ + nc)) * 128 + hm;
    cs_re[o] = are;
    cs_im[o] = aim;
    if (hm == 0) cs_den[bk * NC_ + nc] = aden;
    __syncthreads();
    // phase B: vc[l, hout] = C_chunk(32x256) @ W''(256x32) via MFMA
    int wave = hm >> 6, lane = hm & 63;
    int quad = lane >> 4, l16 = lane & 15;
    f32x4 acc[2];
    acc[0] = (f32x4){0.f, 0.f, 0.f, 0.f};
    acc[1] = (f32x4){0.f, 0.f, 0.f, 0.f};
#pragma unroll
    for (int ks = 0; ks < 8; ++ks) {
        bf16x8 af = *(const bf16x8*)(ct + (size_t)(wave * 16 + l16) * CTS_ + ks * 32 + quad * 8);
        bf16x8 b0 = *(const bf16x8*)(W2B + (size_t)l16 * 256 + ks * 32 + quad * 8);
        bf16x8 b1 = *(const bf16x8*)(W2B + (size_t)(16 + l16) * 256 + ks * 32 + quad * 8);
        acc[0] = __builtin_amdgcn_mfma_f32_16x16x32_bf16(af, b0, acc[0], 0, 0, 0);
        acc[1] = __builtin_amdgcn_mfma_f32_16x16x32_bf16(af, b1, acc[1], 0, 0, 0);
    }
    size_t vbase = (bkL + l0) * 32;
#pragma unroll
    for (int nt = 0; nt < 2; ++nt)
#pragma unroll
        for (int r = 0; r < 4; ++r) {
            int row = wave * 16 + quad * 4 + r;
            vc[vbase + (size_t)row * 32 + nt * 16 + l16] = acc[nt][r];
        }
}

// ---------- pass2: exclusive scan of chunk sums ------------------------------
__global__ void pass2(float* cs_re, float* cs_im, float* cs_den) {
    int seq = blockIdx.x * 256 + threadIdx.x;
    if (seq >= B_ * K_ * 257) return;
    int bk = seq / 257;
    int ch = seq % 257;
    float* base;
    int stride;
    if (ch < 128) { base = cs_re + (size_t)bk * NC_ * 128 + ch; stride = 128; }
    else if (ch < 256) { base = cs_im + (size_t)bk * NC_ * 128 + (ch - 128); stride = 128; }
    else { base = cs_den + (size_t)bk * NC_; stride = 1; }
    float run = 0.f;
#pragma unroll 4
    for (int i = 0; i < NC_; ++i) {
        float v = base[(size_t)i * stride];
        base[(size_t)i * stride] = run;
        run += v;
    }
}

// ---------- scan: fused u_prev matvec + barrier-free scan + gate + store -----
__global__ __launch_bounds__(64) void scan_kernel(const float* __restrict__ zck,
                                                  const float* __restrict__ mask,
                                                  const float* __restrict__ theta_base,
                                                  const float* __restrict__ trs_,
                                                  const float* __restrict__ dslopes,
                                                  const float* __restrict__ aslopes,
                                                  const float* __restrict__ sscale_,
                                                  const ushort* __restrict__ W2B,
                                                  const float* __restrict__ cs_re,
                                                  const float* __restrict__ cs_im,
                                                  const float* __restrict__ cs_den,
                                                  const float* __restrict__ vc,
                                                  ushort* __restrict__ gq) {
    int nc = blockIdx.x, k = blockIdx.y, b = blockIdx.z;
    int lane = threadIdx.x;
    int bk = b * K_ + k;
    size_t bkL = (size_t)bk * L_;
    int h0 = lane >> 2, h1 = 16 + (lane >> 2), m = lane & 3;
    int hout = lane & 31, half = lane >> 5;
    float raw = (k < DH_) ? dslopes[k] : aslopes[k - DH_];
    float slope = log1pf(__expf(raw));
    float sscale = sscale_[k];
    float trsv = trs_[k];
    float tb = theta_base[k * M_ + m];
    const float PI3 = 1.04719755119659775f;

    size_t o = ((size_t)(bk * NC_ + nc)) * 128;
    // u_prev = dot(A_prev, W''[:,hout]) — cs reads are wave-uniform (s_load-able)
    const float* srcp = half ? (cs_im + o) : (cs_re + o);
    float u = 0.f;
#pragma unroll 8
    for (int i = 0; i < 128; ++i)
        u = fmaf(srcp[i], b2f(W2B[hout * 256 + half * 128 + i]), u);
    u += __shfl_xor(u, 32, 64);

    float are0 = cs_re[o + lane];
    float are1 = cs_re[o + 64 + lane];
    float aim0 = cs_im[o + lane];
    float aim1 = cs_im[o + 64 + lane];
    float den = cs_den[bk * NC_ + nc];
    int l0 = nc * CL_;

#pragma unroll 4
    for (int i = 0; i < CL_; ++i) {
        int l = l0 + i;
        const float* zrow = zck + (bkL + l) * ZS_;
        float mval = mask[b * L_ + l];
        float s_raw = zrow[64] * mval;
        float tr = zrow[68 + m];
        float xv0 = zrow[h0] * mval;
        float xv1 = zrow[h1] * mval;
        float arg = fminf(fmaxf(sscale * s_raw, -20.f), 20.f);
        float p = __expf(arg) * mval;
        float tw = (k < DH_) ? __expf(-slope * (float)(L_ - 1 - l)) : __expf(-slope * (float)l);
        float pw = p * tw;
        float td = tr / (1.f + fabsf(tr));
        float theta = tb + trsv * (td * PI3);
        float s0 = __sinf(xv0 * theta), c0 = __cosf(xv0 * theta);
        float s1 = __sinf(xv1 * theta), c1 = __cosf(xv1 * theta);
        // bf16-round to match pass1's sums exactly
        float cre0 = b2f(f2bu(pw * c0)), cim0 = b2f(f2bu(pw * s0));
        float cre1 = b2f(f2bu(pw * c1)), cim1 = b2f(f2bu(pw * s1));
        are0 += cre0; aim0 += cim0; are1 += cre1; aim1 += cim1;
        den += pw;
        float s = are0 * are0 + are1 * are1 + aim0 * aim0 + aim1 * aim1;
#pragma unroll
        for (int off = 32; off; off >>= 1) s += __shfl_xor(s, off, 64);
        float inv = 1.f / fmaxf(den, 1e-4f);
        float rsq = rsqrtf(inv * inv * s * (1.0f / 256.0f) + 1e-5f);
        float scv = inv * rsq;
        // u-prefix + gate + store, fused (lanes>=32 duplicate the u chain)
        u += vc[(bkL + l) * 32 + hout];
        float y = scv * u;
        float zg = zrow[32 + hout];
        float gate = zg / (1.f + __expf(-zg));
        if (lane < 32) gq[(size_t)(b * L_ + l) * D_ + k * H_ + hout] = f2bu(y * gate);
    }
}

extern "C" void kernel_launch(void* const* d_in, const int* in_sizes, int n_in,
                              void* d_out, int out_size, void* d_ws, size_t ws_size,
                              hipStream_t stream) {
    const float* x = (const float*)d_in[0];
    const float* mask = (const float*)d_in[1];
    const float* W_in = (const float*)d_in[2];
    const float* conv_w = (const float*)d_in[3];
    const float* conv_b = (const float*)d_in[4];
    const float* theta_base = (const float*)d_in[5];
    const float* trs = (const float*)d_in[6];
    const float* dsl = (const float*)d_in[7];
    const float* asl = (const float*)d_in[8];
    const float* ssc = (const float*)d_in[9];
    const float* nsc = (const float*)d_in[10];
    const float* Wre = (const float*)d_in[11];
    const float* Wim = (const float*)d_in[12];
    const float* Wout = (const float*)d_in[13];
    float* out = (float*)d_out;

    char* ws = (char*)d_ws;
    // [0, 37.75M): zck
    float* zck = (float*)(ws);
    // [37.75M, 75.5M): z (dead after conv) -> cs_re/cs_im/cs_den/gq
    float* z      = (float*)(ws + 37748736ULL);
    float* cs_re  = (float*)(ws + 37748736ULL);
    float* cs_im  = (float*)(ws + 39845888ULL);
    float* cs_den = (float*)(ws + 41943040ULL);
    ushort* gq    = (ushort*)(ws + 41959424ULL);
    // [75.5M, 88.6M): x_bf + Wt_in (dead after gemm1) -> vc [75.5M, 92.3M)
    ushort* x_bf  = (ushort*)(ws + 75497472ULL);
    ushort* Wt_in = (ushort*)(ws + 83886080ULL);
    float* vc     = (float*)(ws + 75497472ULL);
    // tail: Wt_o, W2B
    ushort* Wt_o  = (ushort*)(ws + 92274688ULL);
    ushort* W2B   = (ushort*)(ws + 94371840ULL);

    convert_x<<<4096, 256, 0, stream>>>((const float4*)x, x_bf);
    transpose_bf16_pad<<<dim3(NPAD_ / 64, 16), 256, 0, stream>>>(W_in, Wt_in, 1024, TOTAL_);
    transpose_bf16_pad<<<dim3(16, 16), 256, 0, stream>>>(Wout, Wt_o, 1024, 1024);
    prep_w2<<<1, 256, 0, stream>>>(Wre, Wim, nsc, W2B);
    gemm_bt<<<dim3(NPAD_ / 128, BL_ / 128), 256, 0, stream>>>(x_bf, Wt_in, z, 1024, NPAD_);
    conv_kernel<<<(BL_ * (TOTAL_ / 4) + 255) / 256, 256, 0, stream>>>(z, conv_w, conv_b, zck);
    pass1<<<dim3(NC_, K_, B_), 128, 0, stream>>>(zck, mask, theta_base, trs, dsl, asl, ssc,
                                                 W2B, cs_re, cs_im, cs_den, vc);
    pass2<<<(B_ * K_ * 257 + 255) / 256, 256, 0, stream>>>(cs_re, cs_im, cs_den);
    scan_kernel<<<dim3(NC_, K_, B_), 64, 0, stream>>>(zck, mask, theta_base, trs, dsl, asl, ssc,
                                                      W2B, cs_re, cs_im, cs_den, vc, gq);
    gemm_bt<<<dim3(D_ / 128, BL_ / 128), 256, 0, stream>>>(gq, Wt_o, out, 1024, 1024);
}